// Round 20
// baseline (174.063 us; speedup 1.0000x reference)
//
#include <hip/hip_runtime.h>
#include <hip/hip_bf16.h>
#include <stdint.h>

typedef unsigned short u16;
typedef __attribute__((ext_vector_type(8))) short bf16x8;
typedef __attribute__((ext_vector_type(4))) float f32x4;
typedef __attribute__((ext_vector_type(16))) float f32x16;
typedef __attribute__((ext_vector_type(4))) short s16x4;
typedef __attribute__((ext_vector_type(2))) unsigned u32x2;

#define SEQ   2048
#define BATCH 4

#define MFMA16(a,b,c) __builtin_amdgcn_mfma_f32_16x16x32_bf16(a,b,c,0,0,0)
#define MFMA32(a,b,c) __builtin_amdgcn_mfma_f32_32x32x16_bf16(a,b,c,0,0,0)
#define EXP2F __builtin_amdgcn_exp2f

__device__ __forceinline__ u16 f2bf(float f) {
  union { float f; uint32_t u; } c{f};
  uint32_t r = c.u + 0x7fffu + ((c.u >> 16) & 1u);   // RNE
  return (u16)(r >> 16);
}

__device__ __forceinline__ void gll16(const void* g, void* l) {
  __builtin_amdgcn_global_load_lds((const __attribute__((address_space(1))) void*)g,
                                   (__attribute__((address_space(3))) void*)l,
                                   16, 0, 0);
}

// Builtin permlane32_swap (compiler-scoreboarded):
__device__ __forceinline__ void plswap(uint32_t &a, uint32_t &b) {
  u32x2 r = __builtin_amdgcn_permlane32_swap(a, b, false, false);
  a = r[0]; b = r[1];
}
__device__ __forceinline__ float xhalf_max(float v) {
  union { float f; uint32_t u; } c{v};
  u32x2 r = __builtin_amdgcn_permlane32_swap(c.u, c.u, false, false);
  union { uint32_t u; float f; } x{r[0]}, y{r[1]};
  return fmaxf(x.f, y.f);
}
__device__ __forceinline__ float xhalf_add(float v) {
  union { float f; uint32_t u; } c{v};
  u32x2 r = __builtin_amdgcn_permlane32_swap(c.u, c.u, false, false);
  union { uint32_t u; float f; } x{r[0]}, y{r[1]};
  return x.f + y.f;
}

// ------------- fused input prep: x->bf16, w_qkv->T, w_out->T -------------
__global__ __launch_bounds__(256) void k_prep(const float* __restrict__ x,
                                              u16* __restrict__ xbf,
                                              const float* __restrict__ wqkv,
                                              u16* __restrict__ wqkvT,
                                              const float* __restrict__ wout,
                                              u16* __restrict__ woutT) {
  __shared__ float tl[32][33];
  const int bid = blockIdx.x, t = threadIdx.x;
  if (bid < 4096) {
    int i = (bid * 256 + t) * 8;
    float4 a = *(const float4*)(x + i);
    float4 b = *(const float4*)(x + i + 4);
    union { u16 u[8]; bf16x8 v; } r;
    r.u[0] = f2bf(a.x); r.u[1] = f2bf(a.y); r.u[2] = f2bf(a.z); r.u[3] = f2bf(a.w);
    r.u[4] = f2bf(b.x); r.u[5] = f2bf(b.y); r.u[6] = f2bf(b.z); r.u[7] = f2bf(b.w);
    *(bf16x8*)(xbf + i) = r.v;
    return;
  }
  const float* in; u16* out; int N, idx, nx;
  if (bid < 4096 + 3072) { in = wqkv; out = wqkvT; N = 3072; idx = bid - 4096; nx = 96; }
  else                   { in = wout; out = woutT; N = 1024; idx = bid - 7168; nx = 32; }
  const int K = 1024;
  const int c0 = (idx % nx) * 32, r0 = (idx / nx) * 32;
  const int tx = t & 31, ty = t >> 5;
#pragma unroll
  for (int j = 0; j < 32; j += 8)
    tl[ty + j][tx] = in[(size_t)(r0 + ty + j) * N + c0 + tx];
  __syncthreads();
#pragma unroll
  for (int j = 0; j < 32; j += 8)
    out[(size_t)(c0 + ty + j) * K + r0 + tx] = f2bf(tl[tx][ty + j]);
}

// ============ 256x128 BK=32 2-phase counted-vmcnt GEMM (v3) ============
// LDS 48KB = 2 buf x {A-h0 8K, A-h1 8K, B 8K} -> 2 blocks/CU co-resident
// (16 waves/CU): cross-block overlap fills barrier-drain stalls (m114).
// Per tile t (buf c=t&1, stages -> c^1), 2 phases:
//  p0: stage A-h0(t+1); read A-h0,B; 8 MFMA; VM1* (retire A-h1(t)); LGKM0; SBAR
//  p1: stage B(t+1), A-h1(t+1); read A-h1 (B-frags reused); 8 MFMA;
//      VM1* (retire A-h0(t+1)+B(t+1)); LGKM0; SBAR
// (1 load/unit) ledger verified incl. prologue (3 loads, VM1 leaves A-h1) and
// tail (VM0 both phases). Buffer-reuse: each unit's readers LGKM0-drained >=1
// barrier before its c^1 slot is re-staged. (*) tail uses VM0.
#define SBAR  asm volatile("s_barrier" ::: "memory")
#define LGKM0 asm volatile("s_waitcnt lgkmcnt(0)" ::: "memory")
#define VM1   asm volatile("s_waitcnt vmcnt(1)" ::: "memory")
#define VM0   asm volatile("s_waitcnt vmcnt(0)" ::: "memory")
#define FEN   asm volatile("" ::: "memory")

template<int OUT_F32, int VSPLIT>
__global__ __launch_bounds__(512, 2) void k_gemm256(const u16* __restrict__ A,
                                                    const u16* __restrict__ BT,
                                                    const float* __restrict__ bias,
                                                    void* __restrict__ Cv,
                                                    u16* __restrict__ vT,
                                                    int N, int K, int NT, int TN) {
  __shared__ alignas(16) char LDS[49152];
  const int t = threadIdx.x;
  const int l = t & 63, w = t >> 6;
  const int wm = w >> 2, wn = w & 3;
  const int lr = l & 15, lg = l >> 4;

  const int nwg = gridDim.x;
  const int cpx = nwg >> 3;
  const int sb = (blockIdx.x & 7) * cpx + (blockIdx.x >> 3);
  const int brow = (sb / TN) * 256, bcol = (sb % TN) * 128;

  // unit = 128 lds-rows x 32 bf16 (64B row), 1 gll16/thread
  auto stageA = [&](int c, int h, int tt) {
    int r = t >> 2, cg = t & 3;
    int grow = brow + (r >> 6) * 128 + h * 64 + (r & 63);
    int gk = tt * 32 + ((cg ^ (r & 3)) * 8);
    gll16(A + (size_t)grow * K + gk, LDS + c * 24576 + h * 8192 + t * 16);
  };
  auto stageB = [&](int c, int tt) {
    int r = t >> 2, cg = t & 3;
    int grow = bcol + r;
    int gk = tt * 32 + ((cg ^ (r & 3)) * 8);
    gll16(BT + (size_t)grow * K + gk, LDS + c * 24576 + 16384 + t * 16);
  };

  f32x4 acc[8][2] = {};
  bf16x8 afr[4], bfr[2];

#define READ_A(c, h)                                                           \
  {                                                                            \
    const char* baseA = LDS + (c) * 24576 + (h) * 8192 + (wm * 64) * 64;       \
    _Pragma("unroll") for (int mi = 0; mi < 4; mi++)                           \
      afr[mi] = *(const bf16x8*)(baseA + (mi * 16 + lr) * 64 +                 \
                                 ((lg ^ (lr & 3)) * 16));                      \
  }
#define READ_B(c)                                                              \
  {                                                                            \
    const char* baseB = LDS + (c) * 24576 + 16384 + (wn * 32) * 64;            \
    _Pragma("unroll") for (int ni = 0; ni < 2; ni++)                           \
      bfr[ni] = *(const bf16x8*)(baseB + (ni * 16 + lr) * 64 +                 \
                                 ((lg ^ (lr & 3)) * 16));                      \
  }
#define DO_MFMA(H)                                                             \
  {                                                                            \
    __builtin_amdgcn_s_setprio(1);                                             \
    _Pragma("unroll") for (int mi = 0; mi < 4; mi++)                           \
      _Pragma("unroll") for (int ni = 0; ni < 2; ni++)                         \
        acc[(H)*4 + mi][ni] = MFMA16(afr[mi], bfr[ni], acc[(H)*4 + mi][ni]);   \
    __builtin_amdgcn_s_setprio(0);                                             \
  }

  // prologue: 3 loads; VM1 retires A-h0(0)+B(0), leaves A-h1(0)
  stageA(0, 0, 0); FEN;
  stageB(0, 0);    FEN;
  stageA(0, 1, 0); FEN;
  VM1; SBAR;

  for (int tt = 0; tt < NT; tt++) {
    const int c = tt & 1;
    // ---- p0: h0 ----
    if (tt + 1 < NT) { stageA(c ^ 1, 0, tt + 1); FEN; }
    READ_A(c, 0); READ_B(c);
    DO_MFMA(0);
    if (tt + 1 < NT) { VM1; } else { VM0; }   // retire A-h1(t)
    LGKM0; SBAR;
    // ---- p1: h1 (B-frags reused) ----
    if (tt + 1 < NT) { stageB(c ^ 1, tt + 1); FEN; stageA(c ^ 1, 1, tt + 1); FEN; }
    READ_A(c, 1);
    DO_MFMA(1);
    if (tt + 1 < NT) { VM1; } else { VM0; }   // retire A-h0(t+1)+B(t+1)
    LGKM0; SBAR;
  }

  const int r0 = brow + wm * 128 + lg * 4;
  const int c0 = bcol + wn * 32 + lr;
#pragma unroll
  for (int ni = 0; ni < 2; ni++) {
    const int col = c0 + ni * 16;
    float bv = bias[col];
#pragma unroll
    for (int mig = 0; mig < 8; mig++) {
      const int row = r0 + mig * 16;
      if (VSPLIT && col >= 2048) {
        const int bb = row >> 11, n0 = row & 2047;
        union { u16 u[4]; s16x4 v; } pk4;
#pragma unroll
        for (int r = 0; r < 4; r++) pk4.u[r] = f2bf(acc[mig][ni][r] + bv);
        *(s16x4*)(vT + ((size_t)(bb * 1024 + col - 2048) * SEQ + n0)) = pk4.v;
      } else {
#pragma unroll
        for (int r = 0; r < 4; r++) {
          float v = acc[mig][ni][r] + bv;
          size_t off = (size_t)(row + r) * N + col;
          if (OUT_F32) ((float*)Cv)[off] = v;
          else         ((u16*)Cv)[off]   = f2bf(v);
        }
      }
    }
  }
}
#undef READ_A
#undef READ_B
#undef DO_MFMA

// ---------------- causal flash attention, v14: dual-Q merged KV loop ----------------
__global__ __launch_bounds__(256, 2) void k_attn(const u16* __restrict__ qkv,
                                                 const u16* __restrict__ vT,
                                                 u16* __restrict__ outp) {
  __shared__ alignas(16) char SB[2][16384];   // per buffer: K [64][128B] | V [64][128B]
  const int t = threadIdx.x, l = t & 63, w = t >> 6;
  const int hi = l >> 5, q = l & 31;
  const int h = blockIdx.x, qp = blockIdx.y, b = blockIdx.z;
  const int bh = b * 16 + h;
  const int srow = t >> 3;
  const int csw = ((t & 7) * 16) ^ ((srow & 7) << 4);
  const int swz = (q & 7) << 4;
  const float SC = 0.18033688011112042f;                // 0.125 * log2(e)

  auto STAGE = [&](char* buf, int kv0) {
    char* lK = buf + w * 1024;
    char* lV = buf + 8192 + w * 1024;
    gll16(qkv + (size_t)(b * SEQ + kv0 + srow) * 3072 + 1024 + h * 64 + (csw >> 1), lK);
    gll16(qkv + (size_t)(b * SEQ + kv0 + srow + 32) * 3072 + 1024 + h * 64 + (csw >> 1), lK + 4096);
    gll16(vT + (size_t)(bh * 64 + srow) * SEQ + kv0 + (csw >> 1), lV);
    gll16(vT + (size_t)(bh * 64 + srow + 32) * SEQ + kv0 + (csw >> 1), lV + 4096);
  };

  auto COMPUTE = [&](const char* Kb, const char* Vb, int kv0, int qr0, int qg,
                     const bf16x8* qf, f32x16& o0, f32x16& o1, f32x16& lv,
                     float& m_run) {
    f32x16 st0 = {}, st1 = {};
    __builtin_amdgcn_s_setprio(1);
#pragma unroll
    for (int c = 0; c < 4; c++) {
      const int cb = c * 32 + hi * 16;
      bf16x8 k0 = *(const bf16x8*)(Kb + q * 128 + (cb ^ swz));
      bf16x8 k1 = *(const bf16x8*)(Kb + (32 + q) * 128 + (cb ^ swz));
      st0 = MFMA32(k0, qf[c], st0);
      st1 = MFMA32(k1, qf[c], st1);
    }
    __builtin_amdgcn_s_setprio(0);
    if (kv0 + 63 > qr0) {
#pragma unroll
      for (int r = 0; r < 16; r++) {
        const int krow = (r & 3) + 8 * (r >> 2) + 4 * hi;
        if (kv0 + krow > qg)      st0[r] = -1e30f;
        if (kv0 + 32 + krow > qg) st1[r] = -1e30f;
      }
    }
    float tmx[16];
#pragma unroll
    for (int r = 0; r < 16; r++) tmx[r] = fmaxf(st0[r], st1[r]);
    float v0 = fmaxf(fmaxf(tmx[0], tmx[1]), tmx[2]);
    float v1 = fmaxf(fmaxf(tmx[3], tmx[4]), tmx[5]);
    float v2 = fmaxf(fmaxf(tmx[6], tmx[7]), tmx[8]);
    float v3 = fmaxf(fmaxf(tmx[9], tmx[10]), tmx[11]);
    float v4 = fmaxf(fmaxf(tmx[12], tmx[13]), tmx[14]);
    float v5 = fmaxf(fmaxf(v0, v1), tmx[15]);
    float v6 = fmaxf(fmaxf(v2, v3), v4);
    float v7 = fmaxf(v5, v6);
    const float vs = xhalf_max(v7) * SC;
    if (__any(vs > m_run + 8.0f)) {
      float mnew = fmaxf(m_run, vs);
      float corr = EXP2F(m_run - mnew);
      m_run = mnew;
#pragma unroll
      for (int r = 0; r < 16; r++) { o0[r] *= corr; o1[r] *= corr; lv[r] *= corr; }
    }
    f32x16 e0 = st0 * SC - m_run;
    f32x16 e1 = st1 * SC - m_run;
    f32x16 p0, p1;
#pragma unroll
    for (int r = 0; r < 16; r++) { p0[r] = EXP2F(e0[r]); p1[r] = EXP2F(e1[r]); }
    lv += p0 + p1;
#pragma unroll
    for (int khb = 0; khb < 2; khb++) {
      uint32_t pk[8];
#pragma unroll
      for (int ii = 0; ii < 8; ii++) {
        float lo = khb ? p1[2 * ii] : p0[2 * ii];
        float hf = khb ? p1[2 * ii + 1] : p0[2 * ii + 1];
        asm("v_cvt_pk_bf16_f32 %0, %1, %2" : "=v"(pk[ii]) : "v"(lo), "v"(hf));
      }
      plswap(pk[0], pk[2]); plswap(pk[1], pk[3]);
      plswap(pk[4], pk[6]); plswap(pk[5], pk[7]);
      union { uint32_t u[4]; bf16x8 v; } be, bo;
      be.u[0] = pk[0]; be.u[1] = pk[1]; be.u[2] = pk[2]; be.u[3] = pk[3];
      bo.u[0] = pk[4]; bo.u[1] = pk[5]; bo.u[2] = pk[6]; bo.u[3] = pk[7];
      __builtin_amdgcn_s_setprio(1);
#pragma unroll
      for (int kti = 0; kti < 2; kti++) {
        const int cb = (khb * 2 + kti) * 32 + hi * 16;
        bf16x8 vv0 = *(const bf16x8*)(Vb + q * 128 + (cb ^ swz));
        bf16x8 vv1 = *(const bf16x8*)(Vb + (32 + q) * 128 + (cb ^ swz));
        bf16x8 pb = kti ? bo.v : be.v;
        o0 = MFMA32(vv0, pb, o0);
        o1 = MFMA32(vv1, pb, o1);
      }
      __builtin_amdgcn_s_setprio(0);
    }
  };

  const int qtA = qp, qtB = 15 - qp;
  const int qr0A = qtA * 128 + w * 32, qgA = qr0A + q;
  const int qr0B = qtB * 128 + w * 32, qgB = qr0B + q;
  bf16x8 qfA[4], qfB[4];
#pragma unroll
  for (int c = 0; c < 4; c++) {
    qfA[c] = *(const bf16x8*)(qkv + (size_t)(b * SEQ + qgA) * 3072 + h * 64 + c * 16 + hi * 8);
    qfB[c] = *(const bf16x8*)(qkv + (size_t)(b * SEQ + qgB) * 3072 + h * 64 + c * 16 + hi * 8);
  }
  f32x16 oA0 = {}, oA1 = {}, lvA = {};
  f32x16 oB0 = {}, oB1 = {}, lvB = {};
  float mA = -1e30f, mB = -1e30f;
  const int nkvB = 2 * qtB + 2;

  STAGE(SB[0], 0);
  for (int j = 0; j < nkvB; j++) {
    const int kv0 = j * 64;
    __syncthreads();
    if (j + 1 < nkvB) STAGE(SB[(j + 1) & 1], kv0 + 64);
    const char* Kb = SB[j & 1];
    const char* Vb = Kb + 8192;
    if (kv0 <= qr0A + 31)
      COMPUTE(Kb, Vb, kv0, qr0A, qgA, qfA, oA0, oA1, lvA, mA);
    if (kv0 <= qr0B + 31)
      COMPUTE(Kb, Vb, kv0, qr0B, qgB, qfB, oB0, oB1, lvB, mB);
  }
#pragma unroll
  for (int sel = 0; sel < 2; sel++) {
    f32x16& o0 = sel ? oB0 : oA0;
    f32x16& o1 = sel ? oB1 : oA1;
    f32x16& lv = sel ? lvB : lvA;
    const int qg = sel ? qgB : qgA;
    float ls = ((lv[0] + lv[1]) + (lv[2] + lv[3])) + ((lv[4] + lv[5]) + (lv[6] + lv[7]))
             + ((lv[8] + lv[9]) + (lv[10] + lv[11])) + ((lv[12] + lv[13]) + (lv[14] + lv[15]));
    ls = xhalf_add(ls);
    const float invl = 1.0f / ls;
#pragma unroll
    for (int dh = 0; dh < 2; dh++)
#pragma unroll
      for (int jq = 0; jq < 4; jq++) {
        union { u16 u[4]; s16x4 v; } pk4;
#pragma unroll
        for (int r = 0; r < 4; r++)
          pk4.u[r] = f2bf((dh ? o1[4 * jq + r] : o0[4 * jq + r]) * invl);
        *(s16x4*)(outp + (size_t)(b * SEQ + qg) * 1024 + h * 64 + dh * 32 + jq * 8 + hi * 4) = pk4.v;
      }
  }
}

extern "C" void kernel_launch(void* const* d_in, const int* in_sizes, int n_in,
                              void* d_out, int out_size, void* d_ws, size_t ws_size,
                              hipStream_t stream) {
  const float* x     = (const float*)d_in[0];
  const float* w_qkv = (const float*)d_in[1];
  const float* b_qkv = (const float*)d_in[2];
  const float* w_out = (const float*)d_in[3];
  const float* b_out = (const float*)d_in[4];

  char* ws = (char*)d_ws;
  u16* xbf   = (u16*)(ws);                       // 16 MB [8192][1024]  (reused as attn_out)
  u16* wqkvT = (u16*)(ws + (16u << 20));         //  6 MB [3072][1024]
  u16* woutT = (u16*)(ws + (22u << 20));         //  2 MB [1024][1024]
  u16* qkvb  = (u16*)(ws + (24u << 20));         // 48 MB [8192][3072] (V third unused)
  u16* vTb   = (u16*)(ws + (72u << 20));         // 16 MB [64][64][2048]

  // fused prep: 4096 (x cvt) + 3072 (w_qkv T) + 1024 (w_out T) blocks
  k_prep<<<8192, 256, 0, stream>>>(x, xbf, w_qkv, wqkvT, w_out, woutT);
  // GEMM1 (VSPLIT): M=8192, N=3072 -> 768 blocks; NT=32 (BK=32)
  k_gemm256<0, 1><<<768, 512, 0, stream>>>(xbf, wqkvT, b_qkv, qkvb, vTb, 3072, 1024, 32, 24);
  // attn: grid (h=16, qp=8, b=4); dual-Q merged KV loop per block
  k_attn<<<dim3(16, 8, 4), 256, 0, stream>>>(qkvb, vTb, xbf);
  // GEMM2: M=8192, N=1024 -> 256 blocks, fp32 out; NT=32
  k_gemm256<1, 0><<<256, 512, 0, stream>>>(xbf, woutT, b_out, d_out, nullptr, 1024, 1024, 32, 8);
}

// Round 21
// 157.584 us; speedup vs baseline: 1.1046x; 1.1046x over previous
//
#include <hip/hip_runtime.h>
#include <hip/hip_bf16.h>
#include <stdint.h>

typedef unsigned short u16;
typedef __attribute__((ext_vector_type(8))) short bf16x8;
typedef __attribute__((ext_vector_type(4))) float f32x4;
typedef __attribute__((ext_vector_type(16))) float f32x16;
typedef __attribute__((ext_vector_type(4))) short s16x4;
typedef __attribute__((ext_vector_type(2))) unsigned u32x2;

#define SEQ   2048
#define BATCH 4

#define MFMA16(a,b,c) __builtin_amdgcn_mfma_f32_16x16x32_bf16(a,b,c,0,0,0)
#define MFMA32(a,b,c) __builtin_amdgcn_mfma_f32_32x32x16_bf16(a,b,c,0,0,0)
#define EXP2F __builtin_amdgcn_exp2f

__device__ __forceinline__ u16 f2bf(float f) {
  union { float f; uint32_t u; } c{f};
  uint32_t r = c.u + 0x7fffu + ((c.u >> 16) & 1u);   // RNE
  return (u16)(r >> 16);
}

__device__ __forceinline__ void gll16(const void* g, void* l) {
  __builtin_amdgcn_global_load_lds((const __attribute__((address_space(1))) void*)g,
                                   (__attribute__((address_space(3))) void*)l,
                                   16, 0, 0);
}

// Builtin permlane32_swap (compiler-scoreboarded):
__device__ __forceinline__ void plswap(uint32_t &a, uint32_t &b) {
  u32x2 r = __builtin_amdgcn_permlane32_swap(a, b, false, false);
  a = r[0]; b = r[1];
}
__device__ __forceinline__ float xhalf_max(float v) {
  union { float f; uint32_t u; } c{v};
  u32x2 r = __builtin_amdgcn_permlane32_swap(c.u, c.u, false, false);
  union { uint32_t u; float f; } x{r[0]}, y{r[1]};
  return fmaxf(x.f, y.f);
}
__device__ __forceinline__ float xhalf_add(float v) {
  union { float f; uint32_t u; } c{v};
  u32x2 r = __builtin_amdgcn_permlane32_swap(c.u, c.u, false, false);
  union { uint32_t u; float f; } x{r[0]}, y{r[1]};
  return x.f + y.f;
}

// ------------- fused input prep: x->bf16, w_qkv->T, w_out->T -------------
__global__ __launch_bounds__(256) void k_prep(const float* __restrict__ x,
                                              u16* __restrict__ xbf,
                                              const float* __restrict__ wqkv,
                                              u16* __restrict__ wqkvT,
                                              const float* __restrict__ wout,
                                              u16* __restrict__ woutT) {
  __shared__ float tl[32][33];
  const int bid = blockIdx.x, t = threadIdx.x;
  if (bid < 4096) {
    int i = (bid * 256 + t) * 8;
    float4 a = *(const float4*)(x + i);
    float4 b = *(const float4*)(x + i + 4);
    union { u16 u[8]; bf16x8 v; } r;
    r.u[0] = f2bf(a.x); r.u[1] = f2bf(a.y); r.u[2] = f2bf(a.z); r.u[3] = f2bf(a.w);
    r.u[4] = f2bf(b.x); r.u[5] = f2bf(b.y); r.u[6] = f2bf(b.z); r.u[7] = f2bf(b.w);
    *(bf16x8*)(xbf + i) = r.v;
    return;
  }
  const float* in; u16* out; int N, idx, nx;
  if (bid < 4096 + 3072) { in = wqkv; out = wqkvT; N = 3072; idx = bid - 4096; nx = 96; }
  else                   { in = wout; out = woutT; N = 1024; idx = bid - 7168; nx = 32; }
  const int K = 1024;
  const int c0 = (idx % nx) * 32, r0 = (idx / nx) * 32;
  const int tx = t & 31, ty = t >> 5;
#pragma unroll
  for (int j = 0; j < 32; j += 8)
    tl[ty + j][tx] = in[(size_t)(r0 + ty + j) * N + c0 + tx];
  __syncthreads();
#pragma unroll
  for (int j = 0; j < 32; j += 8)
    out[(size_t)(c0 + ty + j) * K + r0 + tx] = f2bf(tl[tx][ty + j]);
}

// ====== 256x128 BK=64 2-barrier counted-vmcnt GEMM, single-buffered B ======
// = R19's proven schedule (2 barriers/tile, 32 MFMA/tile, 8-group swizzle,
//   VM2/VM0 ledger with identical counts) with B's double-buffer dropped:
//   ALL B reads (ks0+ks1 -> bfr[2][2]) happen in p0 and are LGKM0-drained
//   before SBAR#1; B(t+1) then stages into the SAME 16KB buffer right after
//   SBAR#1 (cross-wave safe via the barrier). LDS 96KB -> 80KB -> exactly
//   2 blocks/CU (16 waves): cross-block overlap fills the barrier-drain
//   stalls (m114) without R20's conflict/barrier regressions.
#define SBAR  asm volatile("s_barrier" ::: "memory")
#define LGKM0 asm volatile("s_waitcnt lgkmcnt(0)" ::: "memory")
#define VM2   asm volatile("s_waitcnt vmcnt(2)" ::: "memory")
#define VM0   asm volatile("s_waitcnt vmcnt(0)" ::: "memory")
#define FEN   asm volatile("" ::: "memory")

template<int OUT_F32, int VSPLIT>
__global__ __launch_bounds__(512, 2) void k_gemm256(const u16* __restrict__ A,
                                                    const u16* __restrict__ BT,
                                                    const float* __restrict__ bias,
                                                    void* __restrict__ Cv,
                                                    u16* __restrict__ vT,
                                                    int N, int K, int NT, int TN) {
  __shared__ alignas(16) char LDS[81920];   // A: 2 buf x 32K | B: 1 x 16K @65536
  const int t = threadIdx.x;
  const int l = t & 63, w = t >> 6;
  const int wm = w >> 2, wn = w & 3;
  const int lr = l & 15, lg = l >> 4;

  const int nwg = gridDim.x;
  const int cpx = nwg >> 3;
  const int sb = (blockIdx.x & 7) * cpx + (blockIdx.x >> 3);
  const int brow = (sb / TN) * 256, bcol = (sb % TN) * 128;

  auto stageA = [&](int c, int h, int tt) {
#pragma unroll
    for (int i = 0; i < 2; i++) {
      int s = t + i * 512;
      int r = s >> 3, cg = s & 7;
      int grow = brow + (r >> 6) * 128 + h * 64 + (r & 63);
      int gk = tt * 64 + ((cg ^ (r & 7)) * 8);
      gll16(A + (size_t)grow * K + gk, LDS + c * 32768 + h * 16384 + s * 16);
    }
  };
  auto stageB = [&](int tt) {
#pragma unroll
    for (int i = 0; i < 2; i++) {
      int s = t + i * 512;
      int r = s >> 3, cg = s & 7;
      int grow = bcol + r;
      int gk = tt * 64 + ((cg ^ (r & 7)) * 8);
      gll16(BT + (size_t)grow * K + gk, LDS + 65536 + s * 16);
    }
  };

  f32x4 acc[8][2] = {};
  bf16x8 afr[4], bfr[2][2];

#define READ_A(c, h, ks)                                                       \
  {                                                                            \
    const char* baseA = LDS + (c) * 32768 + (h) * 16384 + (wm * 64) * 128;     \
    _Pragma("unroll") for (int mi = 0; mi < 4; mi++)                           \
      afr[mi] = *(const bf16x8*)(baseA + (mi * 16 + lr) * 128 +                \
                                 ((((ks) * 4 + lg) ^ (lr & 7)) * 16));         \
  }
#define READ_B_ALL()                                                           \
  {                                                                            \
    const char* baseB = LDS + 65536 + (wn * 32) * 128;                         \
    _Pragma("unroll") for (int ks = 0; ks < 2; ks++)                           \
      _Pragma("unroll") for (int ni = 0; ni < 2; ni++)                         \
        bfr[ks][ni] = *(const bf16x8*)(baseB + (ni * 16 + lr) * 128 +          \
                                       (((ks * 4 + lg) ^ (lr & 7)) * 16));     \
  }
#define DO_MFMA(H, KS)                                                         \
  {                                                                            \
    __builtin_amdgcn_s_setprio(1);                                             \
    _Pragma("unroll") for (int mi = 0; mi < 4; mi++)                           \
      _Pragma("unroll") for (int ni = 0; ni < 2; ni++)                         \
        acc[(H)*4 + mi][ni] = MFMA16(afr[mi], bfr[KS][ni], acc[(H)*4 + mi][ni]); \
    __builtin_amdgcn_s_setprio(0);                                             \
  }

  // prologue: 6 loads; VM2 retires A-h0(0)+B(0), leaves A-h1(0)
  stageA(0, 0, 0); FEN;
  stageB(0);       FEN;
  stageA(0, 1, 0); FEN;
  VM2; SBAR;

  for (int tt = 0; tt < NT; tt++) {
    const int c = tt & 1;
    // ---- p0: (h0,ks0); ALL B reads here (frees B buffer at SBAR#1) ----
    if (tt + 1 < NT) { stageA(c ^ 1, 0, tt + 1); FEN; }
    READ_A(c, 0, 0); READ_B_ALL();
    DO_MFMA(0, 0);
    if (tt + 1 < NT) { VM2; } else { VM0; }   // retire A-h1(t)
    LGKM0; SBAR;                               // barrier #1: B(t) reads retired everywhere
    // ---- barrier-free zone: (h1,ks0), (h1,ks1), (h0,ks1) ----
    if (tt + 1 < NT) { stageB(tt + 1); FEN; }  // safe: single B buffer freed above
    READ_A(c, 1, 0);
    DO_MFMA(1, 0);
    if (tt + 1 < NT) { stageA(c ^ 1, 1, tt + 1); FEN; }
    READ_A(c, 1, 1);
    DO_MFMA(1, 1);
    READ_A(c, 0, 1);
    DO_MFMA(0, 1);
    if (tt + 1 < NT) { VM2; } else { VM0; }   // retire A-h0(t+1)+B(t+1)
    LGKM0; SBAR;                               // barrier #2: tile handoff
  }

  const int r0 = brow + wm * 128 + lg * 4;
  const int c0 = bcol + wn * 32 + lr;
#pragma unroll
  for (int ni = 0; ni < 2; ni++) {
    const int col = c0 + ni * 16;
    float bv = bias[col];
#pragma unroll
    for (int mig = 0; mig < 8; mig++) {
      const int row = r0 + mig * 16;
      if (VSPLIT && col >= 2048) {
        const int bb = row >> 11, n0 = row & 2047;
        union { u16 u[4]; s16x4 v; } pk4;
#pragma unroll
        for (int r = 0; r < 4; r++) pk4.u[r] = f2bf(acc[mig][ni][r] + bv);
        *(s16x4*)(vT + ((size_t)(bb * 1024 + col - 2048) * SEQ + n0)) = pk4.v;
      } else {
#pragma unroll
        for (int r = 0; r < 4; r++) {
          float v = acc[mig][ni][r] + bv;
          size_t off = (size_t)(row + r) * N + col;
          if (OUT_F32) ((float*)Cv)[off] = v;
          else         ((u16*)Cv)[off]   = f2bf(v);
        }
      }
    }
  }
}
#undef READ_A
#undef READ_B_ALL
#undef DO_MFMA

// ---------------- causal flash attention, v14: dual-Q merged KV loop ----------------
__global__ __launch_bounds__(256, 2) void k_attn(const u16* __restrict__ qkv,
                                                 const u16* __restrict__ vT,
                                                 u16* __restrict__ outp) {
  __shared__ alignas(16) char SB[2][16384];   // per buffer: K [64][128B] | V [64][128B]
  const int t = threadIdx.x, l = t & 63, w = t >> 6;
  const int hi = l >> 5, q = l & 31;
  const int h = blockIdx.x, qp = blockIdx.y, b = blockIdx.z;
  const int bh = b * 16 + h;
  const int srow = t >> 3;
  const int csw = ((t & 7) * 16) ^ ((srow & 7) << 4);
  const int swz = (q & 7) << 4;
  const float SC = 0.18033688011112042f;                // 0.125 * log2(e)

  auto STAGE = [&](char* buf, int kv0) {
    char* lK = buf + w * 1024;
    char* lV = buf + 8192 + w * 1024;
    gll16(qkv + (size_t)(b * SEQ + kv0 + srow) * 3072 + 1024 + h * 64 + (csw >> 1), lK);
    gll16(qkv + (size_t)(b * SEQ + kv0 + srow + 32) * 3072 + 1024 + h * 64 + (csw >> 1), lK + 4096);
    gll16(vT + (size_t)(bh * 64 + srow) * SEQ + kv0 + (csw >> 1), lV);
    gll16(vT + (size_t)(bh * 64 + srow + 32) * SEQ + kv0 + (csw >> 1), lV + 4096);
  };

  auto COMPUTE = [&](const char* Kb, const char* Vb, int kv0, int qr0, int qg,
                     const bf16x8* qf, f32x16& o0, f32x16& o1, f32x16& lv,
                     float& m_run) {
    f32x16 st0 = {}, st1 = {};
    __builtin_amdgcn_s_setprio(1);
#pragma unroll
    for (int c = 0; c < 4; c++) {
      const int cb = c * 32 + hi * 16;
      bf16x8 k0 = *(const bf16x8*)(Kb + q * 128 + (cb ^ swz));
      bf16x8 k1 = *(const bf16x8*)(Kb + (32 + q) * 128 + (cb ^ swz));
      st0 = MFMA32(k0, qf[c], st0);
      st1 = MFMA32(k1, qf[c], st1);
    }
    __builtin_amdgcn_s_setprio(0);
    if (kv0 + 63 > qr0) {
#pragma unroll
      for (int r = 0; r < 16; r++) {
        const int krow = (r & 3) + 8 * (r >> 2) + 4 * hi;
        if (kv0 + krow > qg)      st0[r] = -1e30f;
        if (kv0 + 32 + krow > qg) st1[r] = -1e30f;
      }
    }
    float tmx[16];
#pragma unroll
    for (int r = 0; r < 16; r++) tmx[r] = fmaxf(st0[r], st1[r]);
    float v0 = fmaxf(fmaxf(tmx[0], tmx[1]), tmx[2]);
    float v1 = fmaxf(fmaxf(tmx[3], tmx[4]), tmx[5]);
    float v2 = fmaxf(fmaxf(tmx[6], tmx[7]), tmx[8]);
    float v3 = fmaxf(fmaxf(tmx[9], tmx[10]), tmx[11]);
    float v4 = fmaxf(fmaxf(tmx[12], tmx[13]), tmx[14]);
    float v5 = fmaxf(fmaxf(v0, v1), tmx[15]);
    float v6 = fmaxf(fmaxf(v2, v3), v4);
    float v7 = fmaxf(v5, v6);
    const float vs = xhalf_max(v7) * SC;
    if (__any(vs > m_run + 8.0f)) {
      float mnew = fmaxf(m_run, vs);
      float corr = EXP2F(m_run - mnew);
      m_run = mnew;
#pragma unroll
      for (int r = 0; r < 16; r++) { o0[r] *= corr; o1[r] *= corr; lv[r] *= corr; }
    }
    f32x16 e0 = st0 * SC - m_run;
    f32x16 e1 = st1 * SC - m_run;
    f32x16 p0, p1;
#pragma unroll
    for (int r = 0; r < 16; r++) { p0[r] = EXP2F(e0[r]); p1[r] = EXP2F(e1[r]); }
    lv += p0 + p1;
#pragma unroll
    for (int khb = 0; khb < 2; khb++) {
      uint32_t pk[8];
#pragma unroll
      for (int ii = 0; ii < 8; ii++) {
        float lo = khb ? p1[2 * ii] : p0[2 * ii];
        float hf = khb ? p1[2 * ii + 1] : p0[2 * ii + 1];
        asm("v_cvt_pk_bf16_f32 %0, %1, %2" : "=v"(pk[ii]) : "v"(lo), "v"(hf));
      }
      plswap(pk[0], pk[2]); plswap(pk[1], pk[3]);
      plswap(pk[4], pk[6]); plswap(pk[5], pk[7]);
      union { uint32_t u[4]; bf16x8 v; } be, bo;
      be.u[0] = pk[0]; be.u[1] = pk[1]; be.u[2] = pk[2]; be.u[3] = pk[3];
      bo.u[0] = pk[4]; bo.u[1] = pk[5]; bo.u[2] = pk[6]; bo.u[3] = pk[7];
      __builtin_amdgcn_s_setprio(1);
#pragma unroll
      for (int kti = 0; kti < 2; kti++) {
        const int cb = (khb * 2 + kti) * 32 + hi * 16;
        bf16x8 vv0 = *(const bf16x8*)(Vb + q * 128 + (cb ^ swz));
        bf16x8 vv1 = *(const bf16x8*)(Vb + (32 + q) * 128 + (cb ^ swz));
        bf16x8 pb = kti ? bo.v : be.v;
        o0 = MFMA32(vv0, pb, o0);
        o1 = MFMA32(vv1, pb, o1);
      }
      __builtin_amdgcn_s_setprio(0);
    }
  };

  const int qtA = qp, qtB = 15 - qp;
  const int qr0A = qtA * 128 + w * 32, qgA = qr0A + q;
  const int qr0B = qtB * 128 + w * 32, qgB = qr0B + q;
  bf16x8 qfA[4], qfB[4];
#pragma unroll
  for (int c = 0; c < 4; c++) {
    qfA[c] = *(const bf16x8*)(qkv + (size_t)(b * SEQ + qgA) * 3072 + h * 64 + c * 16 + hi * 8);
    qfB[c] = *(const bf16x8*)(qkv + (size_t)(b * SEQ + qgB) * 3072 + h * 64 + c * 16 + hi * 8);
  }
  f32x16 oA0 = {}, oA1 = {}, lvA = {};
  f32x16 oB0 = {}, oB1 = {}, lvB = {};
  float mA = -1e30f, mB = -1e30f;
  const int nkvB = 2 * qtB + 2;

  STAGE(SB[0], 0);
  for (int j = 0; j < nkvB; j++) {
    const int kv0 = j * 64;
    __syncthreads();
    if (j + 1 < nkvB) STAGE(SB[(j + 1) & 1], kv0 + 64);
    const char* Kb = SB[j & 1];
    const char* Vb = Kb + 8192;
    if (kv0 <= qr0A + 31)
      COMPUTE(Kb, Vb, kv0, qr0A, qgA, qfA, oA0, oA1, lvA, mA);
    if (kv0 <= qr0B + 31)
      COMPUTE(Kb, Vb, kv0, qr0B, qgB, qfB, oB0, oB1, lvB, mB);
  }
#pragma unroll
  for (int sel = 0; sel < 2; sel++) {
    f32x16& o0 = sel ? oB0 : oA0;
    f32x16& o1 = sel ? oB1 : oA1;
    f32x16& lv = sel ? lvB : lvA;
    const int qg = sel ? qgB : qgA;
    float ls = ((lv[0] + lv[1]) + (lv[2] + lv[3])) + ((lv[4] + lv[5]) + (lv[6] + lv[7]))
             + ((lv[8] + lv[9]) + (lv[10] + lv[11])) + ((lv[12] + lv[13]) + (lv[14] + lv[15]));
    ls = xhalf_add(ls);
    const float invl = 1.0f / ls;
#pragma unroll
    for (int dh = 0; dh < 2; dh++)
#pragma unroll
      for (int jq = 0; jq < 4; jq++) {
        union { u16 u[4]; s16x4 v; } pk4;
#pragma unroll
        for (int r = 0; r < 4; r++)
          pk4.u[r] = f2bf((dh ? o1[4 * jq + r] : o0[4 * jq + r]) * invl);
        *(s16x4*)(outp + (size_t)(b * SEQ + qg) * 1024 + h * 64 + dh * 32 + jq * 8 + hi * 4) = pk4.v;
      }
  }
}

extern "C" void kernel_launch(void* const* d_in, const int* in_sizes, int n_in,
                              void* d_out, int out_size, void* d_ws, size_t ws_size,
                              hipStream_t stream) {
  const float* x     = (const float*)d_in[0];
  const float* w_qkv = (const float*)d_in[1];
  const float* b_qkv = (const float*)d_in[2];
  const float* w_out = (const float*)d_in[3];
  const float* b_out = (const float*)d_in[4];

  char* ws = (char*)d_ws;
  u16* xbf   = (u16*)(ws);                       // 16 MB [8192][1024]  (reused as attn_out)
  u16* wqkvT = (u16*)(ws + (16u << 20));         //  6 MB [3072][1024]
  u16* woutT = (u16*)(ws + (22u << 20));         //  2 MB [1024][1024]
  u16* qkvb  = (u16*)(ws + (24u << 20));         // 48 MB [8192][3072] (V third unused)
  u16* vTb   = (u16*)(ws + (72u << 20));         // 16 MB [64][64][2048]

  // fused prep: 4096 (x cvt) + 3072 (w_qkv T) + 1024 (w_out T) blocks
  k_prep<<<8192, 256, 0, stream>>>(x, xbf, w_qkv, wqkvT, w_out, woutT);
  // GEMM1 (VSPLIT): M=8192, N=3072 -> 768 blocks; BK=64, NT=16, 80KB LDS (2/CU)
  k_gemm256<0, 1><<<768, 512, 0, stream>>>(xbf, wqkvT, b_qkv, qkvb, vTb, 3072, 1024, 16, 24);
  // attn: grid (h=16, qp=8, b=4); dual-Q merged KV loop per block
  k_attn<<<dim3(16, 8, 4), 256, 0, stream>>>(qkvb, vTb, xbf);
  // GEMM2: M=8192, N=1024 -> 256 blocks, fp32 out
  k_gemm256<1, 0><<<256, 512, 0, stream>>>(xbf, woutT, b_out, d_out, nullptr, 1024, 1024, 16, 8);
}